// Round 14
// baseline (198.992 us; speedup 1.0000x reference)
//
#include <hip/hip_runtime.h>
#include <hip/hip_bf16.h>
#include <stdint.h>

typedef __attribute__((ext_vector_type(8))) short short8;
typedef __attribute__((ext_vector_type(4))) float f32x4;
typedef __attribute__((ext_vector_type(4))) unsigned int u32x4;
typedef __attribute__((ext_vector_type(2))) unsigned int u32x2;

// Skeleton (fixed in reference) — constexpr so fully-unrolled loops fold
// every index/degree/offset into immediates.
constexpr int kNBR[17][4] = {
    {7, 1, 4, 0}, {0, 2, 0, 0}, {1, 3, 0, 0}, {2, 0, 0, 0},
    {0, 5, 0, 0}, {4, 6, 0, 0}, {5, 0, 0, 0}, {0, 8, 0, 0},
    {7, 9, 11, 14}, {8, 10, 0, 0}, {9, 0, 0, 0}, {8, 12, 0, 0},
    {11, 13, 0, 0}, {12, 0, 0, 0}, {8, 15, 0, 0}, {14, 16, 0, 0},
    {15, 0, 0, 0}};
constexpr int kDEG[17] = {3,2,2,1,2,2,1,2,4,2,1,2,2,1,2,2,1};
constexpr float kRDEG[5] = {0.f, 1.f, 0.5f, 0.33333334f, 0.25f};
// per-wave output-joint tiles, balanced so sum(deg) = 8 per wave
constexpr int kWNT[4] = {3, 4, 5, 5};
constexpr int kWJT[4][5] = {{8, 1, 2, 0, 0},
                            {0, 4, 5, 3, 0},
                            {7, 9, 11, 6, 10},
                            {12, 14, 15, 13, 16}};
// packed per-joint neighbor float-offsets (nb*3 fits in a byte)
constexpr uint32_t kNBO(int i) {
  return (uint32_t)(kNBR[i][0] * 3) | ((uint32_t)(kNBR[i][1] * 3) << 8) |
         ((uint32_t)(kNBR[i][2] * 3) << 16) | ((uint32_t)(kNBR[i][3] * 3) << 24);
}

__device__ inline unsigned short f2bf(float f) {
  union { float f; uint32_t u; } v; v.f = f;
  uint32_t u = v.u;
  uint32_t r = u + 0x7fffu + ((u >> 16) & 1u);  // RNE
  return (unsigned short)(r >> 16);
}
// hardware v_cvt_pk_bf16_f32 (RNE), a in low 16, b in high 16
__device__ inline uint32_t pk2(float a, float b) {
  union { __hip_bfloat162 h; uint32_t u; } v;
  v.h = __float22bfloat162_rn(make_float2(a, b));
  return v.u;
}
__device__ inline f32x4 mfma16(short8 a, short8 b, f32x4 c) {
  return __builtin_amdgcn_mfma_f32_16x16x32_bf16(a, b, c, 0, 0, 0);
}

// ---------------- prep kernel (unchanged from R11) ----------------
__global__ void prep(const float* __restrict__ W1,
                     const float* __restrict__ W2,
                     const float* __restrict__ Wp2,
                     const float* __restrict__ W3,
                     const float* __restrict__ Wp1,
                     const float* __restrict__ b3,
                     const float* __restrict__ bp1,
                     const float* __restrict__ b1,
                     short* __restrict__ W1b,
                     short* __restrict__ W2b,
                     short* __restrict__ Wp2b,
                     short* __restrict__ Mb,
                     float* __restrict__ bp1p) {
  __shared__ float w3s[4096];
  __shared__ float Qs[256];
  const int tid = threadIdx.x;
  const int bx = blockIdx.x;
  if (bx < 272) {
    for (int q = tid; q < 4096; q += 256) w3s[q] = W3[q];
    {
      int ro = tid >> 6, k = tid & 63;
      int r = bx * 4 + ro;
      int f = r / 17, i = r - f * 17;
      int dj = kDEG[i];
      float s = 0.f;
#pragma unroll
      for (int t = 0; t < 4; t++) {
        if (t < dj) {
          int nb = kNBR[i][t];
          s += kRDEG[kDEG[nb]] * Wp1[f * 1088 + nb * 64 + k];
        }
      }
      Qs[ro * 64 + k] = s;
    }
    __syncthreads();
    {
      int ro = tid >> 6, c = tid & 63;
      int r = bx * 4 + ro;
      int f = r / 17, i = r - f * 17;
      float s = 0.f;
#pragma unroll
      for (int k = 0; k < 64; k++) s += Qs[ro * 64 + k] * w3s[k * 64 + c];
      int h = c >> 5;
      int c5 = c & 31;
      int q = (c5 >> 2) & 3;
      int m = ((c5 >> 4) << 2) | (c5 & 3);
      int w = f >> 4, l15 = f & 15;
      Mb[((((w * 17 + i) * 2 + h) * 64) + q * 16 + l15) * 8 + m] = (short)f2bf(s);
    }
  } else if (bx < 360) {
    int q = (bx - 272) * 256 + tid;
    if (q < 4096) {  // W2 k-permuted
      int r = q >> 6, c = q & 63;
      int h = c >> 5, c5 = c & 31;
      int qq = (c5 >> 2) & 3, m = ((c5 >> 4) << 2) | (c5 & 3);
      W2b[r * 64 + h * 32 + qq * 8 + m] = (short)f2bf(W2[q]);
    }
    int q2 = q - 4096;
    if (q2 >= 0 && q2 < 16384) {  // Wp2 k-permuted
      int r = q2 >> 6, c = q2 & 63;
      int h = c >> 5, c5 = c & 31;
      int qq = (c5 >> 2) & 3, m = ((c5 >> 4) << 2) | (c5 & 3);
      Wp2b[r * 64 + h * 32 + qq * 8 + m] = (short)f2bf(Wp2[q2]);
    }
    int q3 = q - 20480;
    if (q3 >= 0 && q3 < 2048) {  // W1b 64x32 K-replicated
      int row = q3 >> 5, k = q3 & 31;
      int c = k & 7;
      short v = 0;
      if (c < 3) v = (short)f2bf(W1[row * 3 + c]);
      else if (k == 3) v = (short)f2bf(b1[row]);  // bias, quad0 slot only
      W1b[q3] = v;
    }
  } else {
    int wv = tid >> 6, l = tid & 63;
    int f = (bx - 360) * 4 + wv;
    float s = 0.f;
#pragma unroll
    for (int i = 0; i < 17; i++) s += Wp1[f * 1088 + i * 64 + l] * b3[l];
#pragma unroll
    for (int off = 32; off > 0; off >>= 1) s += __shfl_down(s, off);
    if (l == 0) bp1p[f] = bp1[f] + s;
  }
}

// ---------------- per-wave specialized body (R14) ----------------
// R11 chain with liveness collapsed per joint: L2 accumulation fused into
// the neighbor (s) loop so packed h1 is transient (ph1q array deleted,
// -64 VGPR), and pool-partial MFMAs fused into the joint (t) loop so
// packed h2 is transient (pkh2q array deleted, -80 VGPR). Register demand
// drops enough for 3 waves/SIMD (launch_bounds(256,3)); Mb2 loads spread
// across the compute loop for latency hiding. No setprio (R13: -14%).
template <int WV>
__device__ __forceinline__ void waveBody(
    const short* __restrict__ Mb2, const short* __restrict__ Wp2p,
    const short* __restrict__ W2p, const float* __restrict__ bp2g,
    float* __restrict__ OUT, float* __restrict__ pbuf,
    float* __restrict__ xs, float* __restrict__ sbias,
    const short8 (&w1f)[4], int bx, int lane, int ln15, int quad) {
  constexpr int NT = kWNT[WV];
  const int xbase = ln15 * 51;
  const int q8 = quad * 8;
  const float bias1 = (quad == 0) ? 1.0f : 0.0f;

  short8 w2f[2][4];
#pragma unroll
  for (int h = 0; h < 2; h++)
#pragma unroll
    for (int ft = 0; ft < 4; ft++)
      w2f[h][ft] = *(const short8*)(W2p + (ft * 16 + ln15) * 64 + h * 32 + quad * 8);

  const short8* mb = (const short8*)Mb2;
  f32x4 zacc[4][2];
#pragma unroll
  for (int w4 = 0; w4 < 4; w4++) {
    zacc[w4][0] = (f32x4){0.f, 0.f, 0.f, 0.f};
    zacc[w4][1] = (f32x4){0.f, 0.f, 0.f, 0.f};
  }

  // ---- fused L1 -> L2 -> pool-partial, per joint ----
#pragma unroll
  for (int t = 0; t < NT; t++) {
    const int j = kWJT[WV][t];
    const int dj = kDEG[j];
    const float wj = kRDEG[dj];
    f32x4 a2[2][4];  // L2 accumulators for this joint, both tiles
#pragma unroll
    for (int g = 0; g < 2; g++)
#pragma unroll
      for (int ft = 0; ft < 4; ft++) a2[g][ft] = (f32x4){0.f, 0.f, 0.f, 0.f};

#pragma unroll
    for (int s = 0; s < 4; s++) {
      if (s < dj) {
        const int i = kNBR[j][s];
        const int di = kDEG[i];
        const float wi = kRDEG[di];
        // all-lane build: quad q supplies neighbor q of joint i, scaled;
        // unused quads (q >= di) contribute 0 via wq.
        const int off = (int)((kNBO(i) >> q8) & 0xffu);
        const int b = xbase + off;
        const float wq = (quad < di) ? wi : 0.f;
        u32x4 pht[2][2];  // transient packed h1 of neighbor i, both tiles
#pragma unroll
        for (int g = 0; g < 2; g++) {
          const float* xsg = xs + g * 816;
          union { short8 s8; u32x4 u; } fr;
          fr.u.x = pk2(xsg[b] * wq, xsg[b + 1] * wq);
          fr.u.y = pk2(xsg[b + 2] * wq, bias1);  // k=3 bias slot (quad0)
          fr.u.z = 0u;
          fr.u.w = 0u;
          f32x4 a[4];
#pragma unroll
          for (int ft = 0; ft < 4; ft++)
            a[ft] = mfma16(w1f[ft], fr.s8, (f32x4){0.f, 0.f, 0.f, 0.f});
          // relu+pack straight into u32x4 quads (B-frag layout, no movs)
          u32x4 q0, q1;
          q0.x = pk2(fmaxf(a[0].x, 0.f), fmaxf(a[0].y, 0.f));
          q0.y = pk2(fmaxf(a[0].z, 0.f), fmaxf(a[0].w, 0.f));
          q0.z = pk2(fmaxf(a[1].x, 0.f), fmaxf(a[1].y, 0.f));
          q0.w = pk2(fmaxf(a[1].z, 0.f), fmaxf(a[1].w, 0.f));
          q1.x = pk2(fmaxf(a[2].x, 0.f), fmaxf(a[2].y, 0.f));
          q1.y = pk2(fmaxf(a[2].z, 0.f), fmaxf(a[2].w, 0.f));
          q1.z = pk2(fmaxf(a[3].x, 0.f), fmaxf(a[3].y, 0.f));
          q1.w = pk2(fmaxf(a[3].z, 0.f), fmaxf(a[3].w, 0.f));
          pht[g][0] = q0;
          pht[g][1] = q1;
        }
        // L2 accumulate immediately; pht dies here
#pragma unroll
        for (int g = 0; g < 2; g++)
#pragma unroll
          for (int h = 0; h < 2; h++) {
            union { u32x4 u; short8 s8; } bf;
            bf.u = pht[g][h];
#pragma unroll
            for (int ft = 0; ft < 4; ft++)
              a2[g][ft] = mfma16(w2f[h][ft], bf.s8, a2[g][ft]);
          }
      }
    }

    // h2 epilogue: scale+bias+relu+pack into transient quads
    u32x4 pkt[2][2];
#pragma unroll
    for (int g = 0; g < 2; g++) {
#pragma unroll
      for (int ft = 0; ft < 4; ft++) {
        int fb = ft * 16 + quad * 4;
        f32x4 bv = *(const f32x4*)&sbias[fb];
        uint32_t lo = pk2(fmaxf(a2[g][ft].x * wj + bv.x, 0.f),
                          fmaxf(a2[g][ft].y * wj + bv.y, 0.f));
        uint32_t hi = pk2(fmaxf(a2[g][ft].z * wj + bv.z, 0.f),
                          fmaxf(a2[g][ft].w * wj + bv.w, 0.f));
        if (ft & 1) { pkt[g][ft >> 1].z = lo; pkt[g][ft >> 1].w = hi; }
        else        { pkt[g][ft >> 1].x = lo; pkt[g][ft >> 1].y = hi; }
      }
    }
    // fused pool-partial: one af load feeds both tiles; pkt dies here
#pragma unroll
    for (int h = 0; h < 2; h++) {
      union { u32x4 u; short8 s8; } bf0, bf1;
      bf0.u = pkt[0][h];
      bf1.u = pkt[1][h];
#pragma unroll
      for (int w4 = 0; w4 < 4; w4++) {
        short8 af = mb[(((w4 * 17 + j) * 2 + h) * 64) + lane];
        zacc[w4][0] = mfma16(af, bf0.s8, zacc[w4][0]);
        zacc[w4][1] = mfma16(af, bf1.s8, zacc[w4][1]);
      }
    }
  }

  // ---- partial writeback (contiguous 1KB per slot, conflict-free) ----
#pragma unroll
  for (int w4 = 0; w4 < 4; w4++)
#pragma unroll
    for (int g = 0; g < 2; g++)
      *(f32x4*)(pbuf + WV * 2048 + (w4 * 2 + g) * 256 + lane * 4) = zacc[w4][g];
  // prefetch Wp2 fragments; latency hides behind the barrier
  short8 wp2f[4][2];
#pragma unroll
  for (int t = 0; t < 4; t++) {
    int ot = WV + 4 * t;
    wp2f[t][0] = *(const short8*)(Wp2p + (ot * 16 + ln15) * 64 + quad * 8);
    wp2f[t][1] = *(const short8*)(Wp2p + (ot * 16 + ln15) * 64 + 32 + quad * 8);
  }
  __syncthreads();  // partials ready (barrier #2 of 2)

  // ---- redundant full reduce: z packed in place (no zb exchange) ----
  u32x4 zpq[2][2];
#pragma unroll
  for (int w4 = 0; w4 < 4; w4++) {
    f32x4 bv = *(const f32x4*)&sbias[64 + w4 * 16 + quad * 4];
#pragma unroll
    for (int g = 0; g < 2; g++) {
      const int gw = w4 * 2 + g;
      f32x4 s0 = *(const f32x4*)(pbuf + 0 * 2048 + gw * 256 + lane * 4);
      f32x4 s1 = *(const f32x4*)(pbuf + 1 * 2048 + gw * 256 + lane * 4);
      f32x4 s2 = *(const f32x4*)(pbuf + 2 * 2048 + gw * 256 + lane * 4);
      f32x4 s3 = *(const f32x4*)(pbuf + 3 * 2048 + gw * 256 + lane * 4);
      f32x4 s = (s0 + s1) + (s2 + s3);
      uint32_t lo = pk2(fmaxf(s.x + bv.x, 0.f), fmaxf(s.y + bv.y, 0.f));
      uint32_t hi = pk2(fmaxf(s.z + bv.z, 0.f), fmaxf(s.w + bv.w, 0.f));
      if (w4 & 1) { zpq[g][w4 >> 1].z = lo; zpq[g][w4 >> 1].w = hi; }
      else        { zpq[g][w4 >> 1].x = lo; zpq[g][w4 >> 1].y = hi; }
    }
  }

  // ---- Pool layer 2: B = zpq (direct), k-permuted Wp2, both tiles ----
  const int e0 = bx * 32;
#pragma unroll
  for (int g = 0; g < 2; g++) {
    union { u32x4 u; short8 s8; } bf0, bf1;
    bf0.u = zpq[g][0];
    bf1.u = zpq[g][1];
    int e0g = e0 + g * 16;
#pragma unroll
    for (int t = 0; t < 4; t++) {
      int ot = WV + 4 * t;
      f32x4 a = mfma16(wp2f[t][0], bf0.s8, (f32x4){0.f, 0.f, 0.f, 0.f});
      a = mfma16(wp2f[t][1], bf1.s8, a);
      int ob = ot * 16 + quad * 4;
      f32x4 bv = *(const f32x4*)&bp2g[ob];
      f32x4 res = a + bv;
      *(f32x4*)(OUT + (size_t)(e0g + ln15) * 256 + ob) = res;
    }
  }
}

// ---------------- main fused kernel ----------------
// 256 threads / 4 waves, dual 16-elem tiles per wave, TWO barriers total.
// LDS = 32768 (partials) + 6528 (xs) + 512 (sbias) = 39808 B (x3 = 120KB).
// launch_bounds(256,3): fused liveness (pkh2q/ph1q arrays deleted) drops
// register demand to ~165 total -> 3 waves/SIMD without spill. (256,4)
// would need <=128 total — R12 proved that spills catastrophically.
__launch_bounds__(256, 3)
__global__ void gcn_main(const float* __restrict__ X,
                         const short* __restrict__ Mb2,
                         const short* __restrict__ Wp2p,
                         const short* __restrict__ W2p,
                         const short* __restrict__ W1b,
                         const float* __restrict__ bp1p,
                         const float* __restrict__ b2g,
                         const float* __restrict__ bp2g,
                         float* __restrict__ OUT) {
  __shared__ __align__(16) float pbuf[8192];   // 32768 B cross-wave partials
  __shared__ __align__(16) float xs[2 * 816];  // 6528 B input stage
  __shared__ __align__(16) float sbias[128];   // b2 | bp1p

  const int tid = threadIdx.x;
  const int wave = tid >> 6;
  const int lane = tid & 63;
  const int ln15 = lane & 15;
  const int quad = lane >> 4;
  const int bx = blockIdx.x;

  // ---- init ----
  for (int q = tid; q < 408; q += 256)
    ((f32x4*)xs)[q] = ((const f32x4*)(X + (size_t)bx * 1632))[q];
  short8 w1f[4];
#pragma unroll
  for (int ft = 0; ft < 4; ft++)
    w1f[ft] = *(const short8*)(W1b + (ft * 16 + (lane & 15)) * 32 + (lane >> 4) * 8);
  if (tid < 128) sbias[tid] = (tid < 64) ? b2g[tid] : bp1p[tid - 64];
  __syncthreads();  // xs, sbias ready (barrier #1 of 2)

  if (wave == 0)
    waveBody<0>(Mb2, Wp2p, W2p, bp2g, OUT, pbuf, xs, sbias, w1f, bx, lane, ln15, quad);
  else if (wave == 1)
    waveBody<1>(Mb2, Wp2p, W2p, bp2g, OUT, pbuf, xs, sbias, w1f, bx, lane, ln15, quad);
  else if (wave == 2)
    waveBody<2>(Mb2, Wp2p, W2p, bp2g, OUT, pbuf, xs, sbias, w1f, bx, lane, ln15, quad);
  else
    waveBody<3>(Mb2, Wp2p, W2p, bp2g, OUT, pbuf, xs, sbias, w1f, bx, lane, ln15, quad);
}

extern "C" void kernel_launch(void* const* d_in, const int* in_sizes, int n_in,
                              void* d_out, int out_size, void* d_ws, size_t ws_size,
                              hipStream_t stream) {
  const float* X = (const float*)d_in[0];
  const float* W1 = (const float*)d_in[2];
  const float* b1 = (const float*)d_in[3];
  const float* W2 = (const float*)d_in[4];
  const float* b2 = (const float*)d_in[5];
  const float* W3 = (const float*)d_in[6];
  const float* b3 = (const float*)d_in[7];
  const float* Wp1 = (const float*)d_in[8];
  const float* bp1 = (const float*)d_in[9];
  const float* Wp2 = (const float*)d_in[10];
  const float* bp2 = (const float*)d_in[11];
  float* OUT = (float*)d_out;
  const int B = in_sizes[0] / 51;

  char* ws = (char*)d_ws;
  short* Mb = (short*)(ws + 0);          // 64*1088*2 = 139264 (k-permuted)
  short* Wp2b = (short*)(ws + 139264);   // 32768 (k-permuted)
  short* W2b = (short*)(ws + 172032);    // 8192 (k-permuted)
  short* W1b = (short*)(ws + 180224);    // 4096 (64x32 K-replicated, +b1)
  float* bp1p = (float*)(ws + 184320);   // 256

  prep<<<376, 256, 0, stream>>>(W1, W2, Wp2, W3, Wp1, b3, bp1, b1,
                                W1b, W2b, Wp2b, Mb, bp1p);
  gcn_main<<<B / 32, 256, 0, stream>>>(X, Mb, Wp2b, W2b, W1b, bp1p,
                                       b2, bp2, OUT);
}

// Round 15
// 148.057 us; speedup vs baseline: 1.3440x; 1.3440x over previous
//
#include <hip/hip_runtime.h>
#include <hip/hip_bf16.h>
#include <stdint.h>

typedef __attribute__((ext_vector_type(8))) short short8;
typedef __attribute__((ext_vector_type(4))) float f32x4;
typedef __attribute__((ext_vector_type(4))) unsigned int u32x4;
typedef __attribute__((ext_vector_type(2))) unsigned int u32x2;

// Skeleton (fixed in reference) — constexpr so fully-unrolled loops fold
// every index/degree/offset into immediates.
constexpr int kNBR[17][4] = {
    {7, 1, 4, 0}, {0, 2, 0, 0}, {1, 3, 0, 0}, {2, 0, 0, 0},
    {0, 5, 0, 0}, {4, 6, 0, 0}, {5, 0, 0, 0}, {0, 8, 0, 0},
    {7, 9, 11, 14}, {8, 10, 0, 0}, {9, 0, 0, 0}, {8, 12, 0, 0},
    {11, 13, 0, 0}, {12, 0, 0, 0}, {8, 15, 0, 0}, {14, 16, 0, 0},
    {15, 0, 0, 0}};
constexpr int kDEG[17] = {3,2,2,1,2,2,1,2,4,2,1,2,2,1,2,2,1};
constexpr float kRDEG[5] = {0.f, 1.f, 0.5f, 0.33333334f, 0.25f};
// per-wave output-joint tiles, balanced so sum(deg) = 8 per wave
constexpr int kWNT[4] = {3, 4, 5, 5};
constexpr int kWJT[4][5] = {{8, 1, 2, 0, 0},
                            {0, 4, 5, 3, 0},
                            {7, 9, 11, 6, 10},
                            {12, 14, 15, 13, 16}};
// packed per-joint neighbor float-offsets (nb*3 fits in a byte)
constexpr uint32_t kNBO(int i) {
  return (uint32_t)(kNBR[i][0] * 3) | ((uint32_t)(kNBR[i][1] * 3) << 8) |
         ((uint32_t)(kNBR[i][2] * 3) << 16) | ((uint32_t)(kNBR[i][3] * 3) << 24);
}

__device__ inline unsigned short f2bf(float f) {
  union { float f; uint32_t u; } v; v.f = f;
  uint32_t u = v.u;
  uint32_t r = u + 0x7fffu + ((u >> 16) & 1u);  // RNE
  return (unsigned short)(r >> 16);
}
// hardware v_cvt_pk_bf16_f32 (RNE), a in low 16, b in high 16
__device__ inline uint32_t pk2(float a, float b) {
  union { __hip_bfloat162 h; uint32_t u; } v;
  v.h = __float22bfloat162_rn(make_float2(a, b));
  return v.u;
}
__device__ inline f32x4 mfma16(short8 a, short8 b, f32x4 c) {
  return __builtin_amdgcn_mfma_f32_16x16x32_bf16(a, b, c, 0, 0, 0);
}

// ---------------- prep kernel (unchanged from R11) ----------------
__global__ void prep(const float* __restrict__ W1,
                     const float* __restrict__ W2,
                     const float* __restrict__ Wp2,
                     const float* __restrict__ W3,
                     const float* __restrict__ Wp1,
                     const float* __restrict__ b3,
                     const float* __restrict__ bp1,
                     const float* __restrict__ b1,
                     short* __restrict__ W1b,
                     short* __restrict__ W2b,
                     short* __restrict__ Wp2b,
                     short* __restrict__ Mb,
                     float* __restrict__ bp1p) {
  __shared__ float w3s[4096];
  __shared__ float Qs[256];
  const int tid = threadIdx.x;
  const int bx = blockIdx.x;
  if (bx < 272) {
    for (int q = tid; q < 4096; q += 256) w3s[q] = W3[q];
    {
      int ro = tid >> 6, k = tid & 63;
      int r = bx * 4 + ro;
      int f = r / 17, i = r - f * 17;
      int dj = kDEG[i];
      float s = 0.f;
#pragma unroll
      for (int t = 0; t < 4; t++) {
        if (t < dj) {
          int nb = kNBR[i][t];
          s += kRDEG[kDEG[nb]] * Wp1[f * 1088 + nb * 64 + k];
        }
      }
      Qs[ro * 64 + k] = s;
    }
    __syncthreads();
    {
      int ro = tid >> 6, c = tid & 63;
      int r = bx * 4 + ro;
      int f = r / 17, i = r - f * 17;
      float s = 0.f;
#pragma unroll
      for (int k = 0; k < 64; k++) s += Qs[ro * 64 + k] * w3s[k * 64 + c];
      int h = c >> 5;
      int c5 = c & 31;
      int q = (c5 >> 2) & 3;
      int m = ((c5 >> 4) << 2) | (c5 & 3);
      int w = f >> 4, l15 = f & 15;
      Mb[((((w * 17 + i) * 2 + h) * 64) + q * 16 + l15) * 8 + m] = (short)f2bf(s);
    }
  } else if (bx < 360) {
    int q = (bx - 272) * 256 + tid;
    if (q < 4096) {  // W2 k-permuted
      int r = q >> 6, c = q & 63;
      int h = c >> 5, c5 = c & 31;
      int qq = (c5 >> 2) & 3, m = ((c5 >> 4) << 2) | (c5 & 3);
      W2b[r * 64 + h * 32 + qq * 8 + m] = (short)f2bf(W2[q]);
    }
    int q2 = q - 4096;
    if (q2 >= 0 && q2 < 16384) {  // Wp2 k-permuted
      int r = q2 >> 6, c = q2 & 63;
      int h = c >> 5, c5 = c & 31;
      int qq = (c5 >> 2) & 3, m = ((c5 >> 4) << 2) | (c5 & 3);
      Wp2b[r * 64 + h * 32 + qq * 8 + m] = (short)f2bf(Wp2[q2]);
    }
    int q3 = q - 20480;
    if (q3 >= 0 && q3 < 2048) {  // W1b 64x32 K-replicated
      int row = q3 >> 5, k = q3 & 31;
      int c = k & 7;
      short v = 0;
      if (c < 3) v = (short)f2bf(W1[row * 3 + c]);
      else if (k == 3) v = (short)f2bf(b1[row]);  // bias, quad0 slot only
      W1b[q3] = v;
    }
  } else {
    int wv = tid >> 6, l = tid & 63;
    int f = (bx - 360) * 4 + wv;
    float s = 0.f;
#pragma unroll
    for (int i = 0; i < 17; i++) s += Wp1[f * 1088 + i * 64 + l] * b3[l];
#pragma unroll
    for (int off = 32; off > 0; off >>= 1) s += __shfl_down(s, off);
    if (l == 0) bp1p[f] = bp1[f] + s;
  }
}

// ---------------- per-wave specialized body (R15 = R14 body) ----------------
// Fused per-joint pipeline (L1 -> L2 -> pool-partial): packed h1/h2 are
// transient, Mb2 loads spread across the compute loop. Run at the proven
// 2-waves/SIMD register budget (R12/R14: any tighter cap spills ~2x cost).
template <int WV>
__device__ __forceinline__ void waveBody(
    const short* __restrict__ Mb2, const short* __restrict__ Wp2p,
    const short* __restrict__ W2p, const float* __restrict__ bp2g,
    float* __restrict__ OUT, float* __restrict__ pbuf,
    float* __restrict__ xs, float* __restrict__ sbias,
    const short8 (&w1f)[4], int bx, int lane, int ln15, int quad) {
  constexpr int NT = kWNT[WV];
  const int xbase = ln15 * 51;
  const int q8 = quad * 8;
  const float bias1 = (quad == 0) ? 1.0f : 0.0f;

  short8 w2f[2][4];
#pragma unroll
  for (int h = 0; h < 2; h++)
#pragma unroll
    for (int ft = 0; ft < 4; ft++)
      w2f[h][ft] = *(const short8*)(W2p + (ft * 16 + ln15) * 64 + h * 32 + quad * 8);

  const short8* mb = (const short8*)Mb2;
  f32x4 zacc[4][2];
#pragma unroll
  for (int w4 = 0; w4 < 4; w4++) {
    zacc[w4][0] = (f32x4){0.f, 0.f, 0.f, 0.f};
    zacc[w4][1] = (f32x4){0.f, 0.f, 0.f, 0.f};
  }

  // ---- fused L1 -> L2 -> pool-partial, per joint ----
#pragma unroll
  for (int t = 0; t < NT; t++) {
    const int j = kWJT[WV][t];
    const int dj = kDEG[j];
    const float wj = kRDEG[dj];
    f32x4 a2[2][4];  // L2 accumulators for this joint, both tiles
#pragma unroll
    for (int g = 0; g < 2; g++)
#pragma unroll
      for (int ft = 0; ft < 4; ft++) a2[g][ft] = (f32x4){0.f, 0.f, 0.f, 0.f};

#pragma unroll
    for (int s = 0; s < 4; s++) {
      if (s < dj) {
        const int i = kNBR[j][s];
        const int di = kDEG[i];
        const float wi = kRDEG[di];
        // all-lane build: quad q supplies neighbor q of joint i, scaled;
        // unused quads (q >= di) contribute 0 via wq.
        const int off = (int)((kNBO(i) >> q8) & 0xffu);
        const int b = xbase + off;
        const float wq = (quad < di) ? wi : 0.f;
        u32x4 pht[2][2];  // transient packed h1 of neighbor i, both tiles
#pragma unroll
        for (int g = 0; g < 2; g++) {
          const float* xsg = xs + g * 816;
          union { short8 s8; u32x4 u; } fr;
          fr.u.x = pk2(xsg[b] * wq, xsg[b + 1] * wq);
          fr.u.y = pk2(xsg[b + 2] * wq, bias1);  // k=3 bias slot (quad0)
          fr.u.z = 0u;
          fr.u.w = 0u;
          f32x4 a[4];
#pragma unroll
          for (int ft = 0; ft < 4; ft++)
            a[ft] = mfma16(w1f[ft], fr.s8, (f32x4){0.f, 0.f, 0.f, 0.f});
          // relu+pack straight into u32x4 quads (B-frag layout, no movs)
          u32x4 q0, q1;
          q0.x = pk2(fmaxf(a[0].x, 0.f), fmaxf(a[0].y, 0.f));
          q0.y = pk2(fmaxf(a[0].z, 0.f), fmaxf(a[0].w, 0.f));
          q0.z = pk2(fmaxf(a[1].x, 0.f), fmaxf(a[1].y, 0.f));
          q0.w = pk2(fmaxf(a[1].z, 0.f), fmaxf(a[1].w, 0.f));
          q1.x = pk2(fmaxf(a[2].x, 0.f), fmaxf(a[2].y, 0.f));
          q1.y = pk2(fmaxf(a[2].z, 0.f), fmaxf(a[2].w, 0.f));
          q1.z = pk2(fmaxf(a[3].x, 0.f), fmaxf(a[3].y, 0.f));
          q1.w = pk2(fmaxf(a[3].z, 0.f), fmaxf(a[3].w, 0.f));
          pht[g][0] = q0;
          pht[g][1] = q1;
        }
        // L2 accumulate immediately; pht dies here
#pragma unroll
        for (int g = 0; g < 2; g++)
#pragma unroll
          for (int h = 0; h < 2; h++) {
            union { u32x4 u; short8 s8; } bf;
            bf.u = pht[g][h];
#pragma unroll
            for (int ft = 0; ft < 4; ft++)
              a2[g][ft] = mfma16(w2f[h][ft], bf.s8, a2[g][ft]);
          }
      }
    }

    // h2 epilogue: scale+bias+relu+pack into transient quads
    u32x4 pkt[2][2];
#pragma unroll
    for (int g = 0; g < 2; g++) {
#pragma unroll
      for (int ft = 0; ft < 4; ft++) {
        int fb = ft * 16 + quad * 4;
        f32x4 bv = *(const f32x4*)&sbias[fb];
        uint32_t lo = pk2(fmaxf(a2[g][ft].x * wj + bv.x, 0.f),
                          fmaxf(a2[g][ft].y * wj + bv.y, 0.f));
        uint32_t hi = pk2(fmaxf(a2[g][ft].z * wj + bv.z, 0.f),
                          fmaxf(a2[g][ft].w * wj + bv.w, 0.f));
        if (ft & 1) { pkt[g][ft >> 1].z = lo; pkt[g][ft >> 1].w = hi; }
        else        { pkt[g][ft >> 1].x = lo; pkt[g][ft >> 1].y = hi; }
      }
    }
    // fused pool-partial: one af load feeds both tiles; pkt dies here
#pragma unroll
    for (int h = 0; h < 2; h++) {
      union { u32x4 u; short8 s8; } bf0, bf1;
      bf0.u = pkt[0][h];
      bf1.u = pkt[1][h];
#pragma unroll
      for (int w4 = 0; w4 < 4; w4++) {
        short8 af = mb[(((w4 * 17 + j) * 2 + h) * 64) + lane];
        zacc[w4][0] = mfma16(af, bf0.s8, zacc[w4][0]);
        zacc[w4][1] = mfma16(af, bf1.s8, zacc[w4][1]);
      }
    }
  }

  // ---- partial writeback (contiguous 1KB per slot, conflict-free) ----
#pragma unroll
  for (int w4 = 0; w4 < 4; w4++)
#pragma unroll
    for (int g = 0; g < 2; g++)
      *(f32x4*)(pbuf + WV * 2048 + (w4 * 2 + g) * 256 + lane * 4) = zacc[w4][g];
  // prefetch Wp2 fragments; latency hides behind the barrier
  short8 wp2f[4][2];
#pragma unroll
  for (int t = 0; t < 4; t++) {
    int ot = WV + 4 * t;
    wp2f[t][0] = *(const short8*)(Wp2p + (ot * 16 + ln15) * 64 + quad * 8);
    wp2f[t][1] = *(const short8*)(Wp2p + (ot * 16 + ln15) * 64 + 32 + quad * 8);
  }
  __syncthreads();  // partials ready (barrier #2 of 2)

  // ---- redundant full reduce: z packed in place (no zb exchange) ----
  u32x4 zpq[2][2];
#pragma unroll
  for (int w4 = 0; w4 < 4; w4++) {
    f32x4 bv = *(const f32x4*)&sbias[64 + w4 * 16 + quad * 4];
#pragma unroll
    for (int g = 0; g < 2; g++) {
      const int gw = w4 * 2 + g;
      f32x4 s0 = *(const f32x4*)(pbuf + 0 * 2048 + gw * 256 + lane * 4);
      f32x4 s1 = *(const f32x4*)(pbuf + 1 * 2048 + gw * 256 + lane * 4);
      f32x4 s2 = *(const f32x4*)(pbuf + 2 * 2048 + gw * 256 + lane * 4);
      f32x4 s3 = *(const f32x4*)(pbuf + 3 * 2048 + gw * 256 + lane * 4);
      f32x4 s = (s0 + s1) + (s2 + s3);
      uint32_t lo = pk2(fmaxf(s.x + bv.x, 0.f), fmaxf(s.y + bv.y, 0.f));
      uint32_t hi = pk2(fmaxf(s.z + bv.z, 0.f), fmaxf(s.w + bv.w, 0.f));
      if (w4 & 1) { zpq[g][w4 >> 1].z = lo; zpq[g][w4 >> 1].w = hi; }
      else        { zpq[g][w4 >> 1].x = lo; zpq[g][w4 >> 1].y = hi; }
    }
  }

  // ---- Pool layer 2: B = zpq (direct), k-permuted Wp2, both tiles ----
  const int e0 = bx * 32;
#pragma unroll
  for (int g = 0; g < 2; g++) {
    union { u32x4 u; short8 s8; } bf0, bf1;
    bf0.u = zpq[g][0];
    bf1.u = zpq[g][1];
    int e0g = e0 + g * 16;
#pragma unroll
    for (int t = 0; t < 4; t++) {
      int ot = WV + 4 * t;
      f32x4 a = mfma16(wp2f[t][0], bf0.s8, (f32x4){0.f, 0.f, 0.f, 0.f});
      a = mfma16(wp2f[t][1], bf1.s8, a);
      int ob = ot * 16 + quad * 4;
      f32x4 bv = *(const f32x4*)&bp2g[ob];
      f32x4 res = a + bv;
      *(f32x4*)(OUT + (size_t)(e0g + ln15) * 256 + ob) = res;
    }
  }
}

// ---------------- main fused kernel ----------------
// 256 threads / 4 waves, dual 16-elem tiles per wave, TWO barriers total.
// LDS = 32768 (partials) + 6528 (xs) + 512 (sbias) = 39808 B.
// launch_bounds(256,2): register equilibrium is ~190 total — R12 (cap 128)
// and R14 (cap ~170) both spilled at 2x the occupancy gain. 2 waves/SIMD
// is the proven operating point; this round isolates the fused-body win
// (Mb2 loads spread through compute) at that budget.
__launch_bounds__(256, 2)
__global__ void gcn_main(const float* __restrict__ X,
                         const short* __restrict__ Mb2,
                         const short* __restrict__ Wp2p,
                         const short* __restrict__ W2p,
                         const short* __restrict__ W1b,
                         const float* __restrict__ bp1p,
                         const float* __restrict__ b2g,
                         const float* __restrict__ bp2g,
                         float* __restrict__ OUT) {
  __shared__ __align__(16) float pbuf[8192];   // 32768 B cross-wave partials
  __shared__ __align__(16) float xs[2 * 816];  // 6528 B input stage
  __shared__ __align__(16) float sbias[128];   // b2 | bp1p

  const int tid = threadIdx.x;
  const int wave = tid >> 6;
  const int lane = tid & 63;
  const int ln15 = lane & 15;
  const int quad = lane >> 4;
  const int bx = blockIdx.x;

  // ---- init ----
  for (int q = tid; q < 408; q += 256)
    ((f32x4*)xs)[q] = ((const f32x4*)(X + (size_t)bx * 1632))[q];
  short8 w1f[4];
#pragma unroll
  for (int ft = 0; ft < 4; ft++)
    w1f[ft] = *(const short8*)(W1b + (ft * 16 + (lane & 15)) * 32 + (lane >> 4) * 8);
  if (tid < 128) sbias[tid] = (tid < 64) ? b2g[tid] : bp1p[tid - 64];
  __syncthreads();  // xs, sbias ready (barrier #1 of 2)

  if (wave == 0)
    waveBody<0>(Mb2, Wp2p, W2p, bp2g, OUT, pbuf, xs, sbias, w1f, bx, lane, ln15, quad);
  else if (wave == 1)
    waveBody<1>(Mb2, Wp2p, W2p, bp2g, OUT, pbuf, xs, sbias, w1f, bx, lane, ln15, quad);
  else if (wave == 2)
    waveBody<2>(Mb2, Wp2p, W2p, bp2g, OUT, pbuf, xs, sbias, w1f, bx, lane, ln15, quad);
  else
    waveBody<3>(Mb2, Wp2p, W2p, bp2g, OUT, pbuf, xs, sbias, w1f, bx, lane, ln15, quad);
}

extern "C" void kernel_launch(void* const* d_in, const int* in_sizes, int n_in,
                              void* d_out, int out_size, void* d_ws, size_t ws_size,
                              hipStream_t stream) {
  const float* X = (const float*)d_in[0];
  const float* W1 = (const float*)d_in[2];
  const float* b1 = (const float*)d_in[3];
  const float* W2 = (const float*)d_in[4];
  const float* b2 = (const float*)d_in[5];
  const float* W3 = (const float*)d_in[6];
  const float* b3 = (const float*)d_in[7];
  const float* Wp1 = (const float*)d_in[8];
  const float* bp1 = (const float*)d_in[9];
  const float* Wp2 = (const float*)d_in[10];
  const float* bp2 = (const float*)d_in[11];
  float* OUT = (float*)d_out;
  const int B = in_sizes[0] / 51;

  char* ws = (char*)d_ws;
  short* Mb = (short*)(ws + 0);          // 64*1088*2 = 139264 (k-permuted)
  short* Wp2b = (short*)(ws + 139264);   // 32768 (k-permuted)
  short* W2b = (short*)(ws + 172032);    // 8192 (k-permuted)
  short* W1b = (short*)(ws + 180224);    // 4096 (64x32 K-replicated, +b1)
  float* bp1p = (float*)(ws + 184320);   // 256

  prep<<<376, 256, 0, stream>>>(W1, W2, Wp2, W3, Wp1, b3, bp1, b1,
                                W1b, W2b, Wp2b, Mb, bp1p);
  gcn_main<<<B / 32, 256, 0, stream>>>(X, Mb, Wp2b, W2b, W1b, bp1p,
                                       b2, bp2, OUT);
}